// Round 14
// baseline (44.893 us; speedup 1.0000x reference)
//
#include <hip/hip_runtime.h>
#include <hip/hip_bf16.h>
#include <math.h>

#define B_   32
#define D_   128
#define L_   512
#define NH_  8
#define DK_  16

#define QKS  18    // Qh/Kh row stride in f16 elems ([512][16] + pad 2)
#define VST  520   // V row stride ([16][512] + pad 8)

#define LOG2E 1.4426950408889634f
#define QSC   (0.25f * LOG2E)          // fold 1/sqrt(dk) * log2(e) into Q
#define SH2   (-11.541560327111707f)   // -8 * log2(e): softmax shift, in MFMA acc

typedef _Float16 h2 __attribute__((ext_vector_type(2)));
typedef _Float16 h4 __attribute__((ext_vector_type(4)));
typedef _Float16 h8 __attribute__((ext_vector_type(8)));
typedef __attribute__((ext_vector_type(4)))  float f32x4;
typedef __attribute__((ext_vector_type(16))) float f32x16;
typedef unsigned int u32x2 __attribute__((ext_vector_type(2)));
typedef unsigned int u32x4 __attribute__((ext_vector_type(4)));

__device__ __forceinline__ unsigned int cvt_pk_u(float a, float b) {
    return __builtin_bit_cast(unsigned int, __builtin_amdgcn_cvt_pkrtz(a, b));
}

#define MFMA_K32(a, b, c) __builtin_amdgcn_mfma_f32_16x16x32_f16((a), (b), (c), 0, 0, 0)
#define MFMA_32(a, b, c)  __builtin_amdgcn_mfma_f32_32x32x16_f16((a), (b), (c), 0, 0, 0)

// ---------------------------------------------------------------------------
// Kernel 0: xt[b][l][d] = (fp16) x[b][d][l]  — LDS-tiled transpose+cast.
// ---------------------------------------------------------------------------
__global__ __launch_bounds__(256) void xcast(
    const float* __restrict__ x,   // [B][D][L]
    _Float16* __restrict__ xt)     // [B][L][D]
{
    __shared__ _Float16 T[64][130];
    const int lt = blockIdx.x;
    const int b  = blockIdx.y;
    const int t  = threadIdx.x;
    const float* xb = x + (size_t)b * D_ * L_;
    _Float16* xtb = xt + (size_t)b * L_ * D_;

    #pragma unroll
    for (int i = t; i < 64 * 128; i += 256) {
        const int l = i & 63, d = i >> 6;
        T[l][d] = (_Float16)xb[(size_t)d * L_ + lt * 64 + l];
    }
    __syncthreads();
    #pragma unroll
    for (int i = t; i < 64 * 128; i += 256) {
        const int d = i & 127, l = i >> 7;
        xtb[(size_t)(lt * 64 + l) * D_ + d] = T[l][d];
    }
}

// ---------------------------------------------------------------------------
// Kernel A: fused attention. 1024 thr = 16 waves (4/SIMD). P1: wave owns
// 32 l (2 l-tiles), 16x16x32 fp16 MFMA. P2: wave owns one 32-m tile
// (loop-invariant Bk); 8 iterations over l-PAIRS = 2 independent
// QK->exp->PV chains per iteration; shift-in-accumulator, raw v_exp_f32,
// permlane32_swap P->A-frag, free Z via constant-1.0 B-frag halves.
// ---------------------------------------------------------------------------
__global__ __launch_bounds__(1024, 4) void attn_mfma(
    const _Float16* __restrict__ xt,  // [B][L][D] fp16
    const float* __restrict__ Wq,     // [NH][B][DK][D]
    const float* __restrict__ Wk,
    const float* __restrict__ Wv,
    _Float16* __restrict__ Ht)        // [B][512][128] fp16 (transposed heads)
{
    __shared__ __attribute__((aligned(16))) _Float16 Qh[512 * QKS];  // 18.4 KB
    __shared__ __attribute__((aligned(16))) _Float16 Kh[512 * QKS];  // 18.4 KB
    __shared__ __attribute__((aligned(16))) _Float16 Vs[16 * VST];   // 16.6 KB

    const int nb = blockIdx.x;
    const int n  = nb >> 5;
    const int b  = nb & 31;
    const int t  = threadIdx.x;
    const int wv = t >> 6;          // wave 0..15
    const int ln = t & 63;
    const int l16 = ln & 15;
    const int g4  = ln >> 4;        // 0..3
    const int lm  = ln & 31;        // 32-tile row/col index
    const int hi  = ln >> 5;        // 0..1

    const _Float16* xtb = xt + (size_t)b * L_ * D_;
    const size_t woff = (size_t)(n * B_ + b) * DK_ * D_;
    const float* pWq = Wq + woff;
    const float* pWk = Wk + woff;
    const float* pWv = Wv + woff;

    // ================= P1: Q,K,V = W @ x  (fp16 16x16x32 MFMA) ============
    f32x4 Qa[2], Ka[2], Va[2];
    #pragma unroll
    for (int lt = 0; lt < 2; ++lt) {
        Qa[lt] = (f32x4){0.f,0.f,0.f,0.f};
        Ka[lt] = (f32x4){0.f,0.f,0.f,0.f};
        Va[lt] = (f32x4){0.f,0.f,0.f,0.f};
    }

    #pragma unroll
    for (int ks = 0; ks < 4; ++ks) {
        const int d0 = ks * 32 + g4 * 8;       // A/B-frag k = 8*g4 + j
        const float* aq = pWq + l16 * D_ + d0;
        const float* ak = pWk + l16 * D_ + d0;
        const float* av = pWv + l16 * D_ + d0;
        const float4 q0 = *(const float4*)aq, q1 = *(const float4*)(aq + 4);
        const float4 k0 = *(const float4*)ak, k1 = *(const float4*)(ak + 4);
        const float4 v0 = *(const float4*)av, v1 = *(const float4*)(av + 4);
        h8 Aq, Ak, Av;
        Aq[0]=(_Float16)q0.x; Aq[1]=(_Float16)q0.y; Aq[2]=(_Float16)q0.z; Aq[3]=(_Float16)q0.w;
        Aq[4]=(_Float16)q1.x; Aq[5]=(_Float16)q1.y; Aq[6]=(_Float16)q1.z; Aq[7]=(_Float16)q1.w;
        Ak[0]=(_Float16)k0.x; Ak[1]=(_Float16)k0.y; Ak[2]=(_Float16)k0.z; Ak[3]=(_Float16)k0.w;
        Ak[4]=(_Float16)k1.x; Ak[5]=(_Float16)k1.y; Ak[6]=(_Float16)k1.z; Ak[7]=(_Float16)k1.w;
        Av[0]=(_Float16)v0.x; Av[1]=(_Float16)v0.y; Av[2]=(_Float16)v0.z; Av[3]=(_Float16)v0.w;
        Av[4]=(_Float16)v1.x; Av[5]=(_Float16)v1.y; Av[6]=(_Float16)v1.z; Av[7]=(_Float16)v1.w;
        #pragma unroll
        for (int lt = 0; lt < 2; ++lt) {
            const int l = wv * 32 + lt * 16 + l16;
            const h8 Bx = *(const h8*)&xtb[(size_t)l * D_ + d0];
            Qa[lt] = MFMA_K32(Aq, Bx, Qa[lt]);
            Ka[lt] = MFMA_K32(Ak, Bx, Ka[lt]);
            Va[lt] = MFMA_K32(Av, Bx, Va[lt]);
        }
    }

    // Q^T (pre-scaled by 0.25*log2e), K^T, V -> LDS.
    #pragma unroll
    for (int lt = 0; lt < 2; ++lt) {
        const int l = wv * 32 + lt * 16 + l16;
        h4 qv, kv;
        #pragma unroll
        for (int r = 0; r < 4; ++r) {
            qv[r] = (_Float16)(Qa[lt][r] * QSC);
            kv[r] = (_Float16)Ka[lt][r];
            Vs[(g4 * 4 + r) * VST + l] = (_Float16)Va[lt][r];
        }
        *(h4*)&Qh[l * QKS + g4 * 4] = qv;
        *(h4*)&Kh[l * QKS + g4 * 4] = kv;
    }
    __syncthreads();

    // ====== P2: one 32-m tile per wave, ILP-2 over l-pairs, free Z =========
    const int m0 = wv * 32;
    const h8 Bk = *(const h8*)&Kh[(m0 + lm) * QKS + 8 * hi];

    f32x16 shiftacc, pvacc;
    #pragma unroll
    for (int i = 0; i < 16; ++i) { shiftacc[i] = SH2; pvacc[i] = 0.f; }

    const bool vsel = (lm < 16);
    const int  vrow = lm & 15;
    const h8 ones8 = {(_Float16)1.f,(_Float16)1.f,(_Float16)1.f,(_Float16)1.f,
                      (_Float16)1.f,(_Float16)1.f,(_Float16)1.f,(_Float16)1.f};

    for (int tp = 0; tp < 8; ++tp) {
        const int lbA = tp * 64;
        const int lbB = lbA + 32;
        // two independent chains (A: l-tile 2tp, B: l-tile 2tp+1)
        const h8 AqA = *(const h8*)&Qh[(lbA + lm) * QKS + 8 * hi];
        const h8 AqB = *(const h8*)&Qh[(lbB + lm) * QKS + 8 * hi];
        const f32x16 scA = MFMA_32(AqA, Bk, shiftacc);  // pre-shifted scores
        const f32x16 scB = MFMA_32(AqB, Bk, shiftacc);

        float pA[16], pB[16];
        #pragma unroll
        for (int r = 0; r < 16; ++r) pA[r] = __builtin_amdgcn_exp2f(scA[r]);
        #pragma unroll
        for (int r = 0; r < 16; ++r) pB[r] = __builtin_amdgcn_exp2f(scB[r]);

        const unsigned int a0 = cvt_pk_u(pA[0],  pA[1]);
        const unsigned int a1 = cvt_pk_u(pA[2],  pA[3]);
        const unsigned int a2 = cvt_pk_u(pA[4],  pA[5]);
        const unsigned int a3 = cvt_pk_u(pA[6],  pA[7]);
        const unsigned int a4 = cvt_pk_u(pA[8],  pA[9]);
        const unsigned int a5 = cvt_pk_u(pA[10], pA[11]);
        const unsigned int a6 = cvt_pk_u(pA[12], pA[13]);
        const unsigned int a7 = cvt_pk_u(pA[14], pA[15]);
        const unsigned int b0 = cvt_pk_u(pB[0],  pB[1]);
        const unsigned int b1 = cvt_pk_u(pB[2],  pB[3]);
        const unsigned int b2 = cvt_pk_u(pB[4],  pB[5]);
        const unsigned int b3 = cvt_pk_u(pB[6],  pB[7]);
        const unsigned int b4 = cvt_pk_u(pB[8],  pB[9]);
        const unsigned int b5 = cvt_pk_u(pB[10], pB[11]);
        const unsigned int b6 = cvt_pk_u(pB[12], pB[13]);
        const unsigned int b7 = cvt_pk_u(pB[14], pB[15]);

        const u32x2 sA02 = __builtin_amdgcn_permlane32_swap(a0, a2, false, false);
        const u32x2 sA13 = __builtin_amdgcn_permlane32_swap(a1, a3, false, false);
        const u32x2 sA46 = __builtin_amdgcn_permlane32_swap(a4, a6, false, false);
        const u32x2 sA57 = __builtin_amdgcn_permlane32_swap(a5, a7, false, false);
        const u32x2 sB02 = __builtin_amdgcn_permlane32_swap(b0, b2, false, false);
        const u32x2 sB13 = __builtin_amdgcn_permlane32_swap(b1, b3, false, false);
        const u32x2 sB46 = __builtin_amdgcn_permlane32_swap(b4, b6, false, false);
        const u32x2 sB57 = __builtin_amdgcn_permlane32_swap(b5, b7, false, false);
        const h8 A1 = __builtin_bit_cast(h8, (u32x4){sA02.x, sA13.x, sA02.y, sA13.y});
        const h8 A2 = __builtin_bit_cast(h8, (u32x4){sA46.x, sA57.x, sA46.y, sA57.y});
        const h8 B1 = __builtin_bit_cast(h8, (u32x4){sB02.x, sB13.x, sB02.y, sB13.y});
        const h8 B2 = __builtin_bit_cast(h8, (u32x4){sB46.x, sB57.x, sB46.y, sB57.y});

        // B-frag: cols 0-15 read V, cols 16-31 are constant 1.0 (Z columns)
        const h8 BvA1r = *(const h8*)&Vs[vrow * VST + lbA + 8 * hi];
        const h8 BvA2r = *(const h8*)&Vs[vrow * VST + lbA + 16 + 8 * hi];
        const h8 BvB1r = *(const h8*)&Vs[vrow * VST + lbB + 8 * hi];
        const h8 BvB2r = *(const h8*)&Vs[vrow * VST + lbB + 16 + 8 * hi];
        const h8 BvA1 = vsel ? BvA1r : ones8;
        const h8 BvA2 = vsel ? BvA2r : ones8;
        const h8 BvB1 = vsel ? BvB1r : ones8;
        const h8 BvB2 = vsel ? BvB2r : ones8;

        pvacc = MFMA_32(A1, BvA1, pvacc);
        pvacc = MFMA_32(A2, BvA2, pvacc);
        pvacc = MFMA_32(B1, BvB1, pvacc);
        pvacc = MFMA_32(B2, BvB2, pvacc);
    }

    // epilogue: Z[mrow] sits in cols 16-31 (lane 16+32hi has col 16).
    const int kk = (NH_ - 1 - n) * 16 + l16;
    const int zlane = 16 + 32 * hi;
    _Float16* Hb = Ht + (size_t)b * 512 * 128;
    #pragma unroll
    for (int r = 0; r < 16; ++r) {
        const int mrow = (r & 3) + 8 * (r >> 2) + 4 * hi;
        const float zr  = __shfl(pvacc[r], zlane);
        const float rzr = __builtin_amdgcn_rcpf(zr);
        if (lm < 16) {
            Hb[(size_t)(m0 + mrow) * 128 + kk] = (_Float16)(pvacc[r] * rzr);
        }
    }
}

// ---------------------------------------------------------------------------
// Kernel B: out[b] = Wo[b] (128x128) @ heads[b] (128x512), fp16 MFMA,
// pure-register. grid (8 col-tiles, 32 b), 512 thr; wave = 16-row m-tile.
// ---------------------------------------------------------------------------
__global__ __launch_bounds__(512) void out_proj_mfma(
    const float* __restrict__ Wo,        // [B][128][128]
    const _Float16* __restrict__ Ht,     // [B][512][128]
    float* __restrict__ out)             // [B][128][512]
{
    const int ct = blockIdx.x;     // col0 = ct*64
    const int b  = blockIdx.y;
    const int t  = threadIdx.x;
    const int wv = t >> 6;
    const int ln = t & 63;
    const int l16 = ln & 15;
    const int g4  = ln >> 4;

    const float* Wb = Wo + (size_t)b * D_ * D_;
    const _Float16* Hb = Ht + (size_t)b * 512 * 128;

    f32x4 acc[4];
    #pragma unroll
    for (int nt = 0; nt < 4; ++nt) acc[nt] = (f32x4){0.f,0.f,0.f,0.f};

    #pragma unroll
    for (int ks = 0; ks < 4; ++ks) {
        const int k0 = ks * 32 + g4 * 8;
        const float* ap = Wb + (size_t)(wv * 16 + l16) * D_ + k0;
        h8 Ah;
        #pragma unroll
        for (int j = 0; j < 8; ++j) Ah[j] = (_Float16)ap[j];
        #pragma unroll
        for (int nt = 0; nt < 4; ++nt) {
            const h8 Bh = *(const h8*)&Hb[(size_t)(ct * 64 + nt * 16 + l16) * 128 + k0];
            acc[nt] = MFMA_K32(Ah, Bh, acc[nt]);
        }
    }

    float* ob = out + (size_t)b * D_ * L_;
    #pragma unroll
    for (int nt = 0; nt < 4; ++nt) {
        #pragma unroll
        for (int r = 0; r < 4; ++r) {
            ob[(size_t)(wv * 16 + g4 * 4 + r) * L_ + ct * 64 + nt * 16 + l16] = acc[nt][r];
        }
    }
}

extern "C" void kernel_launch(void* const* d_in, const int* in_sizes, int n_in,
                              void* d_out, int out_size, void* d_ws, size_t ws_size,
                              hipStream_t stream)
{
    const float* x  = (const float*)d_in[0];
    const float* Wq = (const float*)d_in[1];
    const float* Wk = (const float*)d_in[2];
    const float* Wv = (const float*)d_in[3];
    const float* Wo = (const float*)d_in[4];
    float* out = (float*)d_out;

    _Float16* Ht = (_Float16*)d_ws;                       // 4 MB
    _Float16* xt = Ht + (size_t)B_ * 512 * 128;           // 4 MB

    xcast<<<dim3(8, B_), dim3(256), 0, stream>>>(x, xt);
    attn_mfma<<<dim3(NH_ * B_), dim3(1024), 0, stream>>>(xt, Wq, Wk, Wv, Ht);
    out_proj_mfma<<<dim3(8, B_), dim3(512), 0, stream>>>(Wo, Ht, out);
}

// Round 15
// 40.833 us; speedup vs baseline: 1.0994x; 1.0994x over previous
//
#include <hip/hip_runtime.h>
#include <hip/hip_bf16.h>
#include <math.h>

#define B_   32
#define D_   128
#define L_   512
#define NH_  8
#define DK_  16

#define QKS  18    // Qh/Kh row stride in f16 elems ([512][16] + pad 2)
#define VST  520   // V row stride ([32][512] + pad 8); rows 16-31 = 1.0 (free-Z)

#define LOG2E 1.4426950408889634f
#define QSC   (0.25f * LOG2E)          // fold 1/sqrt(dk) * log2(e) into Q
#define SH2   (-11.541560327111707f)   // -8 * log2(e): softmax shift, in MFMA acc

typedef _Float16 h2 __attribute__((ext_vector_type(2)));
typedef _Float16 h4 __attribute__((ext_vector_type(4)));
typedef _Float16 h8 __attribute__((ext_vector_type(8)));
typedef __attribute__((ext_vector_type(4)))  float f32x4;
typedef __attribute__((ext_vector_type(16))) float f32x16;
typedef unsigned int u32x2 __attribute__((ext_vector_type(2)));
typedef unsigned int u32x4 __attribute__((ext_vector_type(4)));

__device__ __forceinline__ unsigned int cvt_pk_u(float a, float b) {
    return __builtin_bit_cast(unsigned int, __builtin_amdgcn_cvt_pkrtz(a, b));
}

#define MFMA_K32(a, b, c) __builtin_amdgcn_mfma_f32_16x16x32_f16((a), (b), (c), 0, 0, 0)
#define MFMA_32(a, b, c)  __builtin_amdgcn_mfma_f32_32x32x16_f16((a), (b), (c), 0, 0, 0)

// ---------------------------------------------------------------------------
// Kernel 0: xt[b][l][d] = (fp16) x[b][d][l]  — LDS-tiled transpose+cast.
// ---------------------------------------------------------------------------
__global__ __launch_bounds__(256) void xcast(
    const float* __restrict__ x,   // [B][D][L]
    _Float16* __restrict__ xt)     // [B][L][D]
{
    __shared__ _Float16 T[64][130];
    const int lt = blockIdx.x;
    const int b  = blockIdx.y;
    const int t  = threadIdx.x;
    const float* xb = x + (size_t)b * D_ * L_;
    _Float16* xtb = xt + (size_t)b * L_ * D_;

    #pragma unroll
    for (int i = t; i < 64 * 128; i += 256) {
        const int l = i & 63, d = i >> 6;
        T[l][d] = (_Float16)xb[(size_t)d * L_ + lt * 64 + l];
    }
    __syncthreads();
    #pragma unroll
    for (int i = t; i < 64 * 128; i += 256) {
        const int d = i & 127, l = i >> 7;
        xtb[(size_t)(lt * 64 + l) * D_ + d] = T[l][d];
    }
}

// ---------------------------------------------------------------------------
// Kernel A: fused attention (R13 structure + anti-serialization levers).
// 512 thr = 8 waves (2/SIMD fixed by grid=256=1 block/CU), bounds (512,2)
// -> 256-VGPR budget. P1: wave owns 64 l (4 l-tiles). P2: wave owns 64 m
// (2 x 32-m-tiles = 2 chains sharing per-iter LDS reads); shift-in-
// accumulator, raw v_exp_f32, permlane32_swap, free-Z via LDS ones rows;
// explicit next-iter LDS prefetch into named regs.
// ---------------------------------------------------------------------------
__global__ __launch_bounds__(512, 2) void attn_mfma(
    const _Float16* __restrict__ xt,  // [B][L][D] fp16
    const float* __restrict__ Wq,     // [NH][B][DK][D]
    const float* __restrict__ Wk,
    const float* __restrict__ Wv,
    _Float16* __restrict__ Ht)        // [B][512][128] fp16 (transposed heads)
{
    __shared__ __attribute__((aligned(16))) _Float16 Qh[512 * QKS];  // 18.4 KB
    __shared__ __attribute__((aligned(16))) _Float16 Kh[512 * QKS];  // 18.4 KB
    __shared__ __attribute__((aligned(16))) _Float16 Vs[32 * VST];   // 33.3 KB

    const int nb = blockIdx.x;
    const int n  = nb >> 5;
    const int b  = nb & 31;
    const int t  = threadIdx.x;
    const int wv = t >> 6;          // wave 0..7
    const int ln = t & 63;
    const int l16 = ln & 15;
    const int g4  = ln >> 4;        // 0..3
    const int lm  = ln & 31;        // 32-tile row/col index
    const int hi  = ln >> 5;        // 0..1

    const _Float16* xtb = xt + (size_t)b * L_ * D_;
    const size_t woff = (size_t)(n * B_ + b) * DK_ * D_;
    const float* pWq = Wq + woff;
    const float* pWk = Wk + woff;
    const float* pWv = Wv + woff;

    // V rows 16..31 = 1.0 -> PV accumulator cols 16..31 become Z[m].
    {
        const h8 ones8 = {(_Float16)1.f,(_Float16)1.f,(_Float16)1.f,(_Float16)1.f,
                          (_Float16)1.f,(_Float16)1.f,(_Float16)1.f,(_Float16)1.f};
        #pragma unroll
        for (int i = 0; i < 2; ++i) {
            const int c = t + i * 512;                 // 1024 h8-chunks
            const int row = 16 + (c >> 6), cc = (c & 63) * 8;
            *(h8*)&Vs[row * VST + cc] = ones8;
        }
    }

    // ================= P1: Q,K,V = W @ x  (fp16 16x16x32 MFMA) ============
    f32x4 Qa[4], Ka[4], Va[4];
    #pragma unroll
    for (int lt = 0; lt < 4; ++lt) {
        Qa[lt] = (f32x4){0.f,0.f,0.f,0.f};
        Ka[lt] = (f32x4){0.f,0.f,0.f,0.f};
        Va[lt] = (f32x4){0.f,0.f,0.f,0.f};
    }

    #pragma unroll
    for (int ks = 0; ks < 4; ++ks) {
        const int d0 = ks * 32 + g4 * 8;       // A/B-frag k = 8*g4 + j
        const float* aq = pWq + l16 * D_ + d0;
        const float* ak = pWk + l16 * D_ + d0;
        const float* av = pWv + l16 * D_ + d0;
        const float4 q0 = *(const float4*)aq, q1 = *(const float4*)(aq + 4);
        const float4 k0 = *(const float4*)ak, k1 = *(const float4*)(ak + 4);
        const float4 v0 = *(const float4*)av, v1 = *(const float4*)(av + 4);
        h8 Aq, Ak, Av;
        Aq[0]=(_Float16)q0.x; Aq[1]=(_Float16)q0.y; Aq[2]=(_Float16)q0.z; Aq[3]=(_Float16)q0.w;
        Aq[4]=(_Float16)q1.x; Aq[5]=(_Float16)q1.y; Aq[6]=(_Float16)q1.z; Aq[7]=(_Float16)q1.w;
        Ak[0]=(_Float16)k0.x; Ak[1]=(_Float16)k0.y; Ak[2]=(_Float16)k0.z; Ak[3]=(_Float16)k0.w;
        Ak[4]=(_Float16)k1.x; Ak[5]=(_Float16)k1.y; Ak[6]=(_Float16)k1.z; Ak[7]=(_Float16)k1.w;
        Av[0]=(_Float16)v0.x; Av[1]=(_Float16)v0.y; Av[2]=(_Float16)v0.z; Av[3]=(_Float16)v0.w;
        Av[4]=(_Float16)v1.x; Av[5]=(_Float16)v1.y; Av[6]=(_Float16)v1.z; Av[7]=(_Float16)v1.w;
        #pragma unroll
        for (int lt = 0; lt < 4; ++lt) {
            const int l = wv * 64 + lt * 16 + l16;
            const h8 Bx = *(const h8*)&xtb[(size_t)l * D_ + d0];
            Qa[lt] = MFMA_K32(Aq, Bx, Qa[lt]);
            Ka[lt] = MFMA_K32(Ak, Bx, Ka[lt]);
            Va[lt] = MFMA_K32(Av, Bx, Va[lt]);
        }
    }

    // Q^T (pre-scaled by 0.25*log2e), K^T, V -> LDS.
    #pragma unroll
    for (int lt = 0; lt < 4; ++lt) {
        const int l = wv * 64 + lt * 16 + l16;
        h4 qv, kv;
        #pragma unroll
        for (int r = 0; r < 4; ++r) {
            qv[r] = (_Float16)(Qa[lt][r] * QSC);
            kv[r] = (_Float16)Ka[lt][r];
            Vs[(g4 * 4 + r) * VST + l] = (_Float16)Va[lt][r];
        }
        *(h4*)&Qh[l * QKS + g4 * 4] = qv;
        *(h4*)&Kh[l * QKS + g4 * 4] = kv;
    }
    __syncthreads();

    // ====== P2: 2 x 32-m-tiles per wave, shared B-side reads, free Z ======
    const int m0 = wv * 64;
    const h8 Bk0 = *(const h8*)&Kh[(m0 + lm) * QKS + 8 * hi];
    const h8 Bk1 = *(const h8*)&Kh[(m0 + 32 + lm) * QKS + 8 * hi];

    f32x16 shiftacc, pv0, pv1;
    #pragma unroll
    for (int i = 0; i < 16; ++i) { shiftacc[i] = SH2; pv0[i] = 0.f; pv1[i] = 0.f; }

    // prefetch iteration 0 (3 LDS reads, shared by both m-chains)
    h8 Aq_n  = *(const h8*)&Qh[lm * QKS + 8 * hi];
    h8 Bv1_n = *(const h8*)&Vs[lm * VST + 8 * hi];
    h8 Bv2_n = *(const h8*)&Vs[lm * VST + 16 + 8 * hi];

    for (int t32 = 0; t32 < 16; ++t32) {
        const h8 Aq2 = Aq_n, Bv1 = Bv1_n, Bv2 = Bv2_n;
        if (t32 < 15) {
            const int lb = (t32 + 1) * 32;
            Aq_n  = *(const h8*)&Qh[(lb + lm) * QKS + 8 * hi];
            Bv1_n = *(const h8*)&Vs[lm * VST + lb + 8 * hi];
            Bv2_n = *(const h8*)&Vs[lm * VST + lb + 16 + 8 * hi];
        }

        const f32x16 sc0 = MFMA_32(Aq2, Bk0, shiftacc);  // pre-shifted scores
        const f32x16 sc1 = MFMA_32(Aq2, Bk1, shiftacc);

        float pA[16], pB[16];
        #pragma unroll
        for (int r = 0; r < 16; ++r) pA[r] = __builtin_amdgcn_exp2f(sc0[r]);
        #pragma unroll
        for (int r = 0; r < 16; ++r) pB[r] = __builtin_amdgcn_exp2f(sc1[r]);

        const unsigned int a0 = cvt_pk_u(pA[0],  pA[1]);
        const unsigned int a1 = cvt_pk_u(pA[2],  pA[3]);
        const unsigned int a2 = cvt_pk_u(pA[4],  pA[5]);
        const unsigned int a3 = cvt_pk_u(pA[6],  pA[7]);
        const unsigned int a4 = cvt_pk_u(pA[8],  pA[9]);
        const unsigned int a5 = cvt_pk_u(pA[10], pA[11]);
        const unsigned int a6 = cvt_pk_u(pA[12], pA[13]);
        const unsigned int a7 = cvt_pk_u(pA[14], pA[15]);
        const unsigned int b0 = cvt_pk_u(pB[0],  pB[1]);
        const unsigned int b1 = cvt_pk_u(pB[2],  pB[3]);
        const unsigned int b2 = cvt_pk_u(pB[4],  pB[5]);
        const unsigned int b3 = cvt_pk_u(pB[6],  pB[7]);
        const unsigned int b4 = cvt_pk_u(pB[8],  pB[9]);
        const unsigned int b5 = cvt_pk_u(pB[10], pB[11]);
        const unsigned int b6 = cvt_pk_u(pB[12], pB[13]);
        const unsigned int b7 = cvt_pk_u(pB[14], pB[15]);

        const u32x2 sA02 = __builtin_amdgcn_permlane32_swap(a0, a2, false, false);
        const u32x2 sA13 = __builtin_amdgcn_permlane32_swap(a1, a3, false, false);
        const u32x2 sA46 = __builtin_amdgcn_permlane32_swap(a4, a6, false, false);
        const u32x2 sA57 = __builtin_amdgcn_permlane32_swap(a5, a7, false, false);
        const u32x2 sB02 = __builtin_amdgcn_permlane32_swap(b0, b2, false, false);
        const u32x2 sB13 = __builtin_amdgcn_permlane32_swap(b1, b3, false, false);
        const u32x2 sB46 = __builtin_amdgcn_permlane32_swap(b4, b6, false, false);
        const u32x2 sB57 = __builtin_amdgcn_permlane32_swap(b5, b7, false, false);
        const h8 A1m0 = __builtin_bit_cast(h8, (u32x4){sA02.x, sA13.x, sA02.y, sA13.y});
        const h8 A2m0 = __builtin_bit_cast(h8, (u32x4){sA46.x, sA57.x, sA46.y, sA57.y});
        const h8 A1m1 = __builtin_bit_cast(h8, (u32x4){sB02.x, sB13.x, sB02.y, sB13.y});
        const h8 A2m1 = __builtin_bit_cast(h8, (u32x4){sB46.x, sB57.x, sB46.y, sB57.y});

        pv0 = MFMA_32(A1m0, Bv1, pv0);
        pv0 = MFMA_32(A2m0, Bv2, pv0);
        pv1 = MFMA_32(A1m1, Bv1, pv1);
        pv1 = MFMA_32(A2m1, Bv2, pv1);
    }

    // epilogue: Z[mrow] sits in cols 16-31 (lane 16+32hi has col 16).
    const int kk = (NH_ - 1 - n) * 16 + l16;
    const int zlane = 16 + 32 * hi;
    _Float16* Hb = Ht + (size_t)b * 512 * 128;
    #pragma unroll
    for (int r = 0; r < 16; ++r) {
        const int mrow = (r & 3) + 8 * (r >> 2) + 4 * hi;
        const float zr0 = __shfl(pv0[r], zlane);
        const float zr1 = __shfl(pv1[r], zlane);
        const float rz0 = __builtin_amdgcn_rcpf(zr0);
        const float rz1 = __builtin_amdgcn_rcpf(zr1);
        if (lm < 16) {
            Hb[(size_t)(m0 + mrow) * 128 + kk]      = (_Float16)(pv0[r] * rz0);
            Hb[(size_t)(m0 + 32 + mrow) * 128 + kk] = (_Float16)(pv1[r] * rz1);
        }
    }
}

// ---------------------------------------------------------------------------
// Kernel B: out[b] = Wo[b] (128x128) @ heads[b] (128x512), fp16 MFMA,
// pure-register. grid (8 col-tiles, 32 b), 512 thr; wave = 16-row m-tile.
// ---------------------------------------------------------------------------
__global__ __launch_bounds__(512) void out_proj_mfma(
    const float* __restrict__ Wo,        // [B][128][128]
    const _Float16* __restrict__ Ht,     // [B][512][128]
    float* __restrict__ out)             // [B][128][512]
{
    const int ct = blockIdx.x;     // col0 = ct*64
    const int b  = blockIdx.y;
    const int t  = threadIdx.x;
    const int wv = t >> 6;
    const int ln = t & 63;
    const int l16 = ln & 15;
    const int g4  = ln >> 4;

    const float* Wb = Wo + (size_t)b * D_ * D_;
    const _Float16* Hb = Ht + (size_t)b * 512 * 128;

    f32x4 acc[4];
    #pragma unroll
    for (int nt = 0; nt < 4; ++nt) acc[nt] = (f32x4){0.f,0.f,0.f,0.f};

    #pragma unroll
    for (int ks = 0; ks < 4; ++ks) {
        const int k0 = ks * 32 + g4 * 8;
        const float* ap = Wb + (size_t)(wv * 16 + l16) * D_ + k0;
        const float4 w0 = *(const float4*)ap, w1 = *(const float4*)(ap + 4);
        h8 Ah;
        Ah[0]=(_Float16)w0.x; Ah[1]=(_Float16)w0.y; Ah[2]=(_Float16)w0.z; Ah[3]=(_Float16)w0.w;
        Ah[4]=(_Float16)w1.x; Ah[5]=(_Float16)w1.y; Ah[6]=(_Float16)w1.z; Ah[7]=(_Float16)w1.w;
        #pragma unroll
        for (int nt = 0; nt < 4; ++nt) {
            const h8 Bh = *(const h8*)&Hb[(size_t)(ct * 64 + nt * 16 + l16) * 128 + k0];
            acc[nt] = MFMA_K32(Ah, Bh, acc[nt]);
        }
    }

    float* ob = out + (size_t)b * D_ * L_;
    #pragma unroll
    for (int nt = 0; nt < 4; ++nt) {
        #pragma unroll
        for (int r = 0; r < 4; ++r) {
            ob[(size_t)(wv * 16 + g4 * 4 + r) * L_ + ct * 64 + nt * 16 + l16] = acc[nt][r];
        }
    }
}

extern "C" void kernel_launch(void* const* d_in, const int* in_sizes, int n_in,
                              void* d_out, int out_size, void* d_ws, size_t ws_size,
                              hipStream_t stream)
{
    const float* x  = (const float*)d_in[0];
    const float* Wq = (const float*)d_in[1];
    const float* Wk = (const float*)d_in[2];
    const float* Wv = (const float*)d_in[3];
    const float* Wo = (const float*)d_in[4];
    float* out = (float*)d_out;

    _Float16* Ht = (_Float16*)d_ws;                       // 4 MB
    _Float16* xt = Ht + (size_t)B_ * 512 * 128;           // 4 MB

    xcast<<<dim3(8, B_), dim3(256), 0, stream>>>(x, xt);
    attn_mfma<<<dim3(NH_ * B_), dim3(512), 0, stream>>>(xt, Wq, Wk, Wv, Ht);
    out_proj_mfma<<<dim3(8, B_), dim3(512), 0, stream>>>(Wo, Ht, out);
}

// Round 16
// 40.263 us; speedup vs baseline: 1.1150x; 1.0141x over previous
//
#include <hip/hip_runtime.h>
#include <hip/hip_bf16.h>
#include <math.h>

#define B_   32
#define D_   128
#define L_   512
#define NH_  8
#define DK_  16

#define QKS  24    // Qh/Kh row stride in f16 ([512][16] + pad 8): 48B rows, 16B-aligned
#define VST  520   // V row stride ([32][512] + pad 8); rows 16-31 = 1.0 (free-Z)

#define LOG2E 1.4426950408889634f
#define QSC   (0.25f * LOG2E)          // fold 1/sqrt(dk) * log2(e) into Q
#define SH2   (-11.541560327111707f)   // -8 * log2(e): softmax shift, in MFMA acc

typedef _Float16 h2 __attribute__((ext_vector_type(2)));
typedef _Float16 h4 __attribute__((ext_vector_type(4)));
typedef _Float16 h8 __attribute__((ext_vector_type(8)));
typedef __attribute__((ext_vector_type(4)))  float f32x4;
typedef __attribute__((ext_vector_type(16))) float f32x16;
typedef unsigned int u32x2 __attribute__((ext_vector_type(2)));
typedef unsigned int u32x4 __attribute__((ext_vector_type(4)));

__device__ __forceinline__ unsigned int cvt_pk_u(float a, float b) {
    return __builtin_bit_cast(unsigned int, __builtin_amdgcn_cvt_pkrtz(a, b));
}

#define MFMA_K32(a, b, c) __builtin_amdgcn_mfma_f32_16x16x32_f16((a), (b), (c), 0, 0, 0)
#define MFMA_32(a, b, c)  __builtin_amdgcn_mfma_f32_32x32x16_f16((a), (b), (c), 0, 0, 0)

// ---------------------------------------------------------------------------
// Kernel 0: xt[b][l][d] = (fp16) x[b][d][l]  — LDS-tiled transpose+cast.
// ---------------------------------------------------------------------------
__global__ __launch_bounds__(256) void xcast(
    const float* __restrict__ x,   // [B][D][L]
    _Float16* __restrict__ xt)     // [B][L][D]
{
    __shared__ _Float16 T[64][130];
    const int lt = blockIdx.x;
    const int b  = blockIdx.y;
    const int t  = threadIdx.x;
    const float* xb = x + (size_t)b * D_ * L_;
    _Float16* xtb = xt + (size_t)b * L_ * D_;

    #pragma unroll
    for (int i = t; i < 64 * 128; i += 256) {
        const int l = i & 63, d = i >> 6;
        T[l][d] = (_Float16)xb[(size_t)d * L_ + lt * 64 + l];
    }
    __syncthreads();
    #pragma unroll
    for (int i = t; i < 64 * 128; i += 256) {
        const int d = i & 127, l = i >> 7;
        xtb[(size_t)(lt * 64 + l) * D_ + d] = T[l][d];
    }
}

// ---------------------------------------------------------------------------
// Kernel A: fused attention (R13 structure; QKS=24 16B-aligned LDS rows,
// unroll-2 t32 loop for cross-iteration overlap). 512 thr = 8 waves,
// bounds (512,2) -> 256-VGPR budget. P1: wave owns 64 l (4 l-tiles).
// P2: wave owns 64 m (2 x 32-m-tiles sharing per-iter LDS reads);
// shift-in-accumulator, raw v_exp_f32, permlane32_swap, free-Z ones rows.
// ---------------------------------------------------------------------------
__global__ __launch_bounds__(512, 2) void attn_mfma(
    const _Float16* __restrict__ xt,  // [B][L][D] fp16
    const float* __restrict__ Wq,     // [NH][B][DK][D]
    const float* __restrict__ Wk,
    const float* __restrict__ Wv,
    _Float16* __restrict__ Ht)        // [B][512][128] fp16 (transposed heads)
{
    __shared__ __attribute__((aligned(16))) _Float16 Qh[512 * QKS];  // 24.6 KB
    __shared__ __attribute__((aligned(16))) _Float16 Kh[512 * QKS];  // 24.6 KB
    __shared__ __attribute__((aligned(16))) _Float16 Vs[32 * VST];   // 33.3 KB

    const int nb = blockIdx.x;
    const int n  = nb >> 5;
    const int b  = nb & 31;
    const int t  = threadIdx.x;
    const int wv = t >> 6;          // wave 0..7
    const int ln = t & 63;
    const int l16 = ln & 15;
    const int g4  = ln >> 4;        // 0..3
    const int lm  = ln & 31;        // 32-tile row/col index
    const int hi  = ln >> 5;        // 0..1

    const _Float16* xtb = xt + (size_t)b * L_ * D_;
    const size_t woff = (size_t)(n * B_ + b) * DK_ * D_;
    const float* pWq = Wq + woff;
    const float* pWk = Wk + woff;
    const float* pWv = Wv + woff;

    // V rows 16..31 = 1.0 -> PV accumulator cols 16..31 become Z[m].
    {
        const h8 ones8 = {(_Float16)1.f,(_Float16)1.f,(_Float16)1.f,(_Float16)1.f,
                          (_Float16)1.f,(_Float16)1.f,(_Float16)1.f,(_Float16)1.f};
        #pragma unroll
        for (int i = 0; i < 2; ++i) {
            const int c = t + i * 512;                 // 1024 h8-chunks
            const int row = 16 + (c >> 6), cc = (c & 63) * 8;
            *(h8*)&Vs[row * VST + cc] = ones8;
        }
    }

    // ================= P1: Q,K,V = W @ x  (fp16 16x16x32 MFMA) ============
    f32x4 Qa[4], Ka[4], Va[4];
    #pragma unroll
    for (int lt = 0; lt < 4; ++lt) {
        Qa[lt] = (f32x4){0.f,0.f,0.f,0.f};
        Ka[lt] = (f32x4){0.f,0.f,0.f,0.f};
        Va[lt] = (f32x4){0.f,0.f,0.f,0.f};
    }

    #pragma unroll
    for (int ks = 0; ks < 4; ++ks) {
        const int d0 = ks * 32 + g4 * 8;       // A/B-frag k = 8*g4 + j
        const float* aq = pWq + l16 * D_ + d0;
        const float* ak = pWk + l16 * D_ + d0;
        const float* av = pWv + l16 * D_ + d0;
        const float4 q0 = *(const float4*)aq, q1 = *(const float4*)(aq + 4);
        const float4 k0 = *(const float4*)ak, k1 = *(const float4*)(ak + 4);
        const float4 v0 = *(const float4*)av, v1 = *(const float4*)(av + 4);
        h8 Aq, Ak, Av;
        Aq[0]=(_Float16)q0.x; Aq[1]=(_Float16)q0.y; Aq[2]=(_Float16)q0.z; Aq[3]=(_Float16)q0.w;
        Aq[4]=(_Float16)q1.x; Aq[5]=(_Float16)q1.y; Aq[6]=(_Float16)q1.z; Aq[7]=(_Float16)q1.w;
        Ak[0]=(_Float16)k0.x; Ak[1]=(_Float16)k0.y; Ak[2]=(_Float16)k0.z; Ak[3]=(_Float16)k0.w;
        Ak[4]=(_Float16)k1.x; Ak[5]=(_Float16)k1.y; Ak[6]=(_Float16)k1.z; Ak[7]=(_Float16)k1.w;
        Av[0]=(_Float16)v0.x; Av[1]=(_Float16)v0.y; Av[2]=(_Float16)v0.z; Av[3]=(_Float16)v0.w;
        Av[4]=(_Float16)v1.x; Av[5]=(_Float16)v1.y; Av[6]=(_Float16)v1.z; Av[7]=(_Float16)v1.w;
        #pragma unroll
        for (int lt = 0; lt < 4; ++lt) {
            const int l = wv * 64 + lt * 16 + l16;
            const h8 Bx = *(const h8*)&xtb[(size_t)l * D_ + d0];
            Qa[lt] = MFMA_K32(Aq, Bx, Qa[lt]);
            Ka[lt] = MFMA_K32(Ak, Bx, Ka[lt]);
            Va[lt] = MFMA_K32(Av, Bx, Va[lt]);
        }
    }

    // Q^T (pre-scaled by 0.25*log2e), K^T, V -> LDS.
    #pragma unroll
    for (int lt = 0; lt < 4; ++lt) {
        const int l = wv * 64 + lt * 16 + l16;
        h4 qv, kv;
        #pragma unroll
        for (int r = 0; r < 4; ++r) {
            qv[r] = (_Float16)(Qa[lt][r] * QSC);
            kv[r] = (_Float16)Ka[lt][r];
            Vs[(g4 * 4 + r) * VST + l] = (_Float16)Va[lt][r];
        }
        *(h4*)&Qh[l * QKS + g4 * 4] = qv;
        *(h4*)&Kh[l * QKS + g4 * 4] = kv;
    }
    __syncthreads();

    // ====== P2: 2 x 32-m-tiles per wave, shared B-side reads, free Z ======
    const int m0 = wv * 64;
    const h8 Bk0 = *(const h8*)&Kh[(m0 + lm) * QKS + 8 * hi];
    const h8 Bk1 = *(const h8*)&Kh[(m0 + 32 + lm) * QKS + 8 * hi];

    f32x16 shiftacc, pv0, pv1;
    #pragma unroll
    for (int i = 0; i < 16; ++i) { shiftacc[i] = SH2; pv0[i] = 0.f; pv1[i] = 0.f; }

    #pragma unroll 2
    for (int t32 = 0; t32 < 16; ++t32) {
        const int lb = t32 * 32;
        const h8 Aq2 = *(const h8*)&Qh[(lb + lm) * QKS + 8 * hi];
        const h8 Bv1 = *(const h8*)&Vs[lm * VST + lb + 8 * hi];
        const h8 Bv2 = *(const h8*)&Vs[lm * VST + lb + 16 + 8 * hi];

        const f32x16 sc0 = MFMA_32(Aq2, Bk0, shiftacc);  // pre-shifted scores
        const f32x16 sc1 = MFMA_32(Aq2, Bk1, shiftacc);

        float pA[16], pB[16];
        #pragma unroll
        for (int r = 0; r < 16; ++r) pA[r] = __builtin_amdgcn_exp2f(sc0[r]);
        #pragma unroll
        for (int r = 0; r < 16; ++r) pB[r] = __builtin_amdgcn_exp2f(sc1[r]);

        const unsigned int a0 = cvt_pk_u(pA[0],  pA[1]);
        const unsigned int a1 = cvt_pk_u(pA[2],  pA[3]);
        const unsigned int a2 = cvt_pk_u(pA[4],  pA[5]);
        const unsigned int a3 = cvt_pk_u(pA[6],  pA[7]);
        const unsigned int a4 = cvt_pk_u(pA[8],  pA[9]);
        const unsigned int a5 = cvt_pk_u(pA[10], pA[11]);
        const unsigned int a6 = cvt_pk_u(pA[12], pA[13]);
        const unsigned int a7 = cvt_pk_u(pA[14], pA[15]);
        const unsigned int b0 = cvt_pk_u(pB[0],  pB[1]);
        const unsigned int b1 = cvt_pk_u(pB[2],  pB[3]);
        const unsigned int b2 = cvt_pk_u(pB[4],  pB[5]);
        const unsigned int b3 = cvt_pk_u(pB[6],  pB[7]);
        const unsigned int b4 = cvt_pk_u(pB[8],  pB[9]);
        const unsigned int b5 = cvt_pk_u(pB[10], pB[11]);
        const unsigned int b6 = cvt_pk_u(pB[12], pB[13]);
        const unsigned int b7 = cvt_pk_u(pB[14], pB[15]);

        const u32x2 sA02 = __builtin_amdgcn_permlane32_swap(a0, a2, false, false);
        const u32x2 sA13 = __builtin_amdgcn_permlane32_swap(a1, a3, false, false);
        const u32x2 sA46 = __builtin_amdgcn_permlane32_swap(a4, a6, false, false);
        const u32x2 sA57 = __builtin_amdgcn_permlane32_swap(a5, a7, false, false);
        const u32x2 sB02 = __builtin_amdgcn_permlane32_swap(b0, b2, false, false);
        const u32x2 sB13 = __builtin_amdgcn_permlane32_swap(b1, b3, false, false);
        const u32x2 sB46 = __builtin_amdgcn_permlane32_swap(b4, b6, false, false);
        const u32x2 sB57 = __builtin_amdgcn_permlane32_swap(b5, b7, false, false);
        const h8 A1m0 = __builtin_bit_cast(h8, (u32x4){sA02.x, sA13.x, sA02.y, sA13.y});
        const h8 A2m0 = __builtin_bit_cast(h8, (u32x4){sA46.x, sA57.x, sA46.y, sA57.y});
        const h8 A1m1 = __builtin_bit_cast(h8, (u32x4){sB02.x, sB13.x, sB02.y, sB13.y});
        const h8 A2m1 = __builtin_bit_cast(h8, (u32x4){sB46.x, sB57.x, sB46.y, sB57.y});

        pv0 = MFMA_32(A1m0, Bv1, pv0);
        pv0 = MFMA_32(A2m0, Bv2, pv0);
        pv1 = MFMA_32(A1m1, Bv1, pv1);
        pv1 = MFMA_32(A2m1, Bv2, pv1);
    }

    // epilogue: Z[mrow] sits in cols 16-31 (lane 16+32hi has col 16).
    const int kk = (NH_ - 1 - n) * 16 + l16;
    const int zlane = 16 + 32 * hi;
    _Float16* Hb = Ht + (size_t)b * 512 * 128;
    #pragma unroll
    for (int r = 0; r < 16; ++r) {
        const int mrow = (r & 3) + 8 * (r >> 2) + 4 * hi;
        const float zr0 = __shfl(pv0[r], zlane);
        const float zr1 = __shfl(pv1[r], zlane);
        const float rz0 = __builtin_amdgcn_rcpf(zr0);
        const float rz1 = __builtin_amdgcn_rcpf(zr1);
        if (lm < 16) {
            Hb[(size_t)(m0 + mrow) * 128 + kk]      = (_Float16)(pv0[r] * rz0);
            Hb[(size_t)(m0 + 32 + mrow) * 128 + kk] = (_Float16)(pv1[r] * rz1);
        }
    }
}

// ---------------------------------------------------------------------------
// Kernel B: out[b] = Wo[b] (128x128) @ heads[b] (128x512), fp16 MFMA,
// pure-register. grid (8 col-tiles, 32 b), 512 thr; wave = 16-row m-tile.
// ---------------------------------------------------------------------------
__global__ __launch_bounds__(512) void out_proj_mfma(
    const float* __restrict__ Wo,        // [B][128][128]
    const _Float16* __restrict__ Ht,     // [B][512][128]
    float* __restrict__ out)             // [B][128][512]
{
    const int ct = blockIdx.x;     // col0 = ct*64
    const int b  = blockIdx.y;
    const int t  = threadIdx.x;
    const int wv = t >> 6;
    const int ln = t & 63;
    const int l16 = ln & 15;
    const int g4  = ln >> 4;

    const float* Wb = Wo + (size_t)b * D_ * D_;
    const _Float16* Hb = Ht + (size_t)b * 512 * 128;

    f32x4 acc[4];
    #pragma unroll
    for (int nt = 0; nt < 4; ++nt) acc[nt] = (f32x4){0.f,0.f,0.f,0.f};

    #pragma unroll
    for (int ks = 0; ks < 4; ++ks) {
        const int k0 = ks * 32 + g4 * 8;
        const float* ap = Wb + (size_t)(wv * 16 + l16) * D_ + k0;
        const float4 w0 = *(const float4*)ap, w1 = *(const float4*)(ap + 4);
        h8 Ah;
        Ah[0]=(_Float16)w0.x; Ah[1]=(_Float16)w0.y; Ah[2]=(_Float16)w0.z; Ah[3]=(_Float16)w0.w;
        Ah[4]=(_Float16)w1.x; Ah[5]=(_Float16)w1.y; Ah[6]=(_Float16)w1.z; Ah[7]=(_Float16)w1.w;
        #pragma unroll
        for (int nt = 0; nt < 4; ++nt) {
            const h8 Bh = *(const h8*)&Hb[(size_t)(ct * 64 + nt * 16 + l16) * 128 + k0];
            acc[nt] = MFMA_K32(Ah, Bh, acc[nt]);
        }
    }

    float* ob = out + (size_t)b * D_ * L_;
    #pragma unroll
    for (int nt = 0; nt < 4; ++nt) {
        #pragma unroll
        for (int r = 0; r < 4; ++r) {
            ob[(size_t)(wv * 16 + g4 * 4 + r) * L_ + ct * 64 + nt * 16 + l16] = acc[nt][r];
        }
    }
}

extern "C" void kernel_launch(void* const* d_in, const int* in_sizes, int n_in,
                              void* d_out, int out_size, void* d_ws, size_t ws_size,
                              hipStream_t stream)
{
    const float* x  = (const float*)d_in[0];
    const float* Wq = (const float*)d_in[1];
    const float* Wk = (const float*)d_in[2];
    const float* Wv = (const float*)d_in[3];
    const float* Wo = (const float*)d_in[4];
    float* out = (float*)d_out;

    _Float16* Ht = (_Float16*)d_ws;                       // 4 MB
    _Float16* xt = Ht + (size_t)B_ * 512 * 128;           // 4 MB

    xcast<<<dim3(8, B_), dim3(256), 0, stream>>>(x, xt);
    attn_mfma<<<dim3(NH_ * B_), dim3(512), 0, stream>>>(xt, Wq, Wk, Wv, Ht);
    out_proj_mfma<<<dim3(8, B_), dim3(512), 0, stream>>>(Wo, Ht, out);
}

// Round 17
// 34.949 us; speedup vs baseline: 1.2845x; 1.1521x over previous
//
#include <hip/hip_runtime.h>
#include <hip/hip_bf16.h>
#include <math.h>

#define B_   32
#define D_   128
#define L_   512
#define NH_  8
#define DK_  16

#define QKS  24    // Qh/Kh row stride in f16 ([512][16] + pad 8): 48B rows, 16B-aligned
#define VST  520   // V row stride ([32][512] + pad 8); rows 16-31 = 1.0 (free-Z)
#define XST  40    // x-stage row stride ([512][32] + pad 8): 80B rows, 16B-aligned

#define LOG2E 1.4426950408889634f
#define QSC   (0.25f * LOG2E)          // fold 1/sqrt(dk) * log2(e) into Q
#define SH2   (-11.541560327111707f)   // -8 * log2(e): softmax shift, in MFMA acc

typedef _Float16 h2 __attribute__((ext_vector_type(2)));
typedef _Float16 h4 __attribute__((ext_vector_type(4)));
typedef _Float16 h8 __attribute__((ext_vector_type(8)));
typedef __attribute__((ext_vector_type(4)))  float f32x4;
typedef __attribute__((ext_vector_type(16))) float f32x16;
typedef unsigned int u32x2 __attribute__((ext_vector_type(2)));
typedef unsigned int u32x4 __attribute__((ext_vector_type(4)));

__device__ __forceinline__ unsigned int cvt_pk_u(float a, float b) {
    return __builtin_bit_cast(unsigned int, __builtin_amdgcn_cvt_pkrtz(a, b));
}

#define MFMA_K32(a, b, c) __builtin_amdgcn_mfma_f32_16x16x32_f16((a), (b), (c), 0, 0, 0)
#define MFMA_32(a, b, c)  __builtin_amdgcn_mfma_f32_32x32x16_f16((a), (b), (c), 0, 0, 0)

// ---------------------------------------------------------------------------
// Kernel A: fused attention with IN-KERNEL x transpose (xcast deleted).
// 512 thr = 8 waves, bounds (512,2). Per ks: stage x[32d][512l] fp32 ->
// LDS T32[l][d] fp16 (coalesced float4 loads, register transpose, h8
// writes), barrier, P1 MFMAs read B-frags from T32. P2 identical to R16:
// 2 x 32-m-tiles/wave, shift-in-acc, raw v_exp_f32, permlane32_swap,
// free-Z ones rows, QKS=24 aligned strides.
// ---------------------------------------------------------------------------
__global__ __launch_bounds__(512, 2) void attn_mfma(
    const float* __restrict__ x,      // [B][D][L] fp32
    const float* __restrict__ Wq,     // [NH][B][DK][D]
    const float* __restrict__ Wk,
    const float* __restrict__ Wv,
    _Float16* __restrict__ Ht)        // [B][512][128] fp16 (transposed heads)
{
    __shared__ __attribute__((aligned(16))) _Float16 T32[512 * XST]; // 40 KB
    __shared__ __attribute__((aligned(16))) _Float16 Qh[512 * QKS];  // 24.6 KB
    __shared__ __attribute__((aligned(16))) _Float16 Kh[512 * QKS];  // 24.6 KB
    __shared__ __attribute__((aligned(16))) _Float16 Vs[32 * VST];   // 33.3 KB

    const int nb = blockIdx.x;
    const int n  = nb >> 5;
    const int b  = nb & 31;
    const int t  = threadIdx.x;
    const int wv = t >> 6;          // wave 0..7
    const int ln = t & 63;
    const int l16 = ln & 15;
    const int g4  = ln >> 4;        // 0..3
    const int lm  = ln & 31;        // 32-tile row/col index
    const int hi  = ln >> 5;        // 0..1

    const float* xb = x + (size_t)b * D_ * L_;
    const size_t woff = (size_t)(n * B_ + b) * DK_ * D_;
    const float* pWq = Wq + woff;
    const float* pWk = Wk + woff;
    const float* pWv = Wv + woff;

    // V rows 16..31 = 1.0 -> PV accumulator cols 16..31 become Z[m].
    {
        const h8 ones8 = {(_Float16)1.f,(_Float16)1.f,(_Float16)1.f,(_Float16)1.f,
                          (_Float16)1.f,(_Float16)1.f,(_Float16)1.f,(_Float16)1.f};
        #pragma unroll
        for (int i = 0; i < 2; ++i) {
            const int c = t + i * 512;                 // 1024 h8-chunks
            const int row = 16 + (c >> 6), cc = (c & 63) * 8;
            *(h8*)&Vs[row * VST + cc] = ones8;
        }
    }

    // staging assignment: thread t handles d-octet dd = t>>7, l-quad l0
    const int sdd = (t >> 7) * 8;          // 0,8,16,24 (local d base)
    const int sl0 = (t & 127) * 4;         // l base 0..508

    // ================= P1: Q,K,V = W @ x  (fp16 16x16x32 MFMA) ============
    f32x4 Qa[4], Ka[4], Va[4];
    #pragma unroll
    for (int lt = 0; lt < 4; ++lt) {
        Qa[lt] = (f32x4){0.f,0.f,0.f,0.f};
        Ka[lt] = (f32x4){0.f,0.f,0.f,0.f};
        Va[lt] = (f32x4){0.f,0.f,0.f,0.f};
    }

    for (int ks = 0; ks < 4; ++ks) {
        // ---- stage x-tile [32 d][512 l] -> T32[l][d] fp16 ----
        {
            f32x4 xv[8];
            #pragma unroll
            for (int j = 0; j < 8; ++j)
                xv[j] = *(const f32x4*)&xb[(size_t)(ks * 32 + sdd + j) * L_ + sl0];
            #pragma unroll
            for (int i = 0; i < 4; ++i) {
                h8 w;
                #pragma unroll
                for (int j = 0; j < 8; ++j) w[j] = (_Float16)xv[j][i];
                *(h8*)&T32[(sl0 + i) * XST + sdd] = w;
            }
        }
        __syncthreads();

        const int d0 = ks * 32 + g4 * 8;       // A/B-frag k = 8*g4 + j
        const float* aq = pWq + l16 * D_ + d0;
        const float* ak = pWk + l16 * D_ + d0;
        const float* av = pWv + l16 * D_ + d0;
        const f32x4 q0 = *(const f32x4*)aq, q1 = *(const f32x4*)(aq + 4);
        const f32x4 k0 = *(const f32x4*)ak, k1 = *(const f32x4*)(ak + 4);
        const f32x4 v0 = *(const f32x4*)av, v1 = *(const f32x4*)(av + 4);
        h8 Aq, Ak, Av;
        #pragma unroll
        for (int j = 0; j < 4; ++j) {
            Aq[j] = (_Float16)q0[j]; Aq[j + 4] = (_Float16)q1[j];
            Ak[j] = (_Float16)k0[j]; Ak[j + 4] = (_Float16)k1[j];
            Av[j] = (_Float16)v0[j]; Av[j + 4] = (_Float16)v1[j];
        }
        #pragma unroll
        for (int lt = 0; lt < 4; ++lt) {
            const int l = wv * 64 + lt * 16 + l16;
            const h8 Bx = *(const h8*)&T32[l * XST + g4 * 8];
            Qa[lt] = MFMA_K32(Aq, Bx, Qa[lt]);
            Ka[lt] = MFMA_K32(Ak, Bx, Ka[lt]);
            Va[lt] = MFMA_K32(Av, Bx, Va[lt]);
        }
        __syncthreads();   // protect T32 before next ks overwrites
    }

    // Q^T (pre-scaled by 0.25*log2e), K^T, V -> LDS.
    #pragma unroll
    for (int lt = 0; lt < 4; ++lt) {
        const int l = wv * 64 + lt * 16 + l16;
        h4 qv, kv;
        #pragma unroll
        for (int r = 0; r < 4; ++r) {
            qv[r] = (_Float16)(Qa[lt][r] * QSC);
            kv[r] = (_Float16)Ka[lt][r];
            Vs[(g4 * 4 + r) * VST + l] = (_Float16)Va[lt][r];
        }
        *(h4*)&Qh[l * QKS + g4 * 4] = qv;
        *(h4*)&Kh[l * QKS + g4 * 4] = kv;
    }
    __syncthreads();

    // ====== P2: 2 x 32-m-tiles per wave, shared B-side reads, free Z ======
    const int m0 = wv * 64;
    const h8 Bk0 = *(const h8*)&Kh[(m0 + lm) * QKS + 8 * hi];
    const h8 Bk1 = *(const h8*)&Kh[(m0 + 32 + lm) * QKS + 8 * hi];

    f32x16 shiftacc, pv0, pv1;
    #pragma unroll
    for (int i = 0; i < 16; ++i) { shiftacc[i] = SH2; pv0[i] = 0.f; pv1[i] = 0.f; }

    #pragma unroll 2
    for (int t32 = 0; t32 < 16; ++t32) {
        const int lb = t32 * 32;
        const h8 Aq2 = *(const h8*)&Qh[(lb + lm) * QKS + 8 * hi];
        const h8 Bv1 = *(const h8*)&Vs[lm * VST + lb + 8 * hi];
        const h8 Bv2 = *(const h8*)&Vs[lm * VST + lb + 16 + 8 * hi];

        const f32x16 sc0 = MFMA_32(Aq2, Bk0, shiftacc);  // pre-shifted scores
        const f32x16 sc1 = MFMA_32(Aq2, Bk1, shiftacc);

        float pA[16], pB[16];
        #pragma unroll
        for (int r = 0; r < 16; ++r) pA[r] = __builtin_amdgcn_exp2f(sc0[r]);
        #pragma unroll
        for (int r = 0; r < 16; ++r) pB[r] = __builtin_amdgcn_exp2f(sc1[r]);

        const unsigned int a0 = cvt_pk_u(pA[0],  pA[1]);
        const unsigned int a1 = cvt_pk_u(pA[2],  pA[3]);
        const unsigned int a2 = cvt_pk_u(pA[4],  pA[5]);
        const unsigned int a3 = cvt_pk_u(pA[6],  pA[7]);
        const unsigned int a4 = cvt_pk_u(pA[8],  pA[9]);
        const unsigned int a5 = cvt_pk_u(pA[10], pA[11]);
        const unsigned int a6 = cvt_pk_u(pA[12], pA[13]);
        const unsigned int a7 = cvt_pk_u(pA[14], pA[15]);
        const unsigned int b0 = cvt_pk_u(pB[0],  pB[1]);
        const unsigned int b1 = cvt_pk_u(pB[2],  pB[3]);
        const unsigned int b2 = cvt_pk_u(pB[4],  pB[5]);
        const unsigned int b3 = cvt_pk_u(pB[6],  pB[7]);
        const unsigned int b4 = cvt_pk_u(pB[8],  pB[9]);
        const unsigned int b5 = cvt_pk_u(pB[10], pB[11]);
        const unsigned int b6 = cvt_pk_u(pB[12], pB[13]);
        const unsigned int b7 = cvt_pk_u(pB[14], pB[15]);

        const u32x2 sA02 = __builtin_amdgcn_permlane32_swap(a0, a2, false, false);
        const u32x2 sA13 = __builtin_amdgcn_permlane32_swap(a1, a3, false, false);
        const u32x2 sA46 = __builtin_amdgcn_permlane32_swap(a4, a6, false, false);
        const u32x2 sA57 = __builtin_amdgcn_permlane32_swap(a5, a7, false, false);
        const u32x2 sB02 = __builtin_amdgcn_permlane32_swap(b0, b2, false, false);
        const u32x2 sB13 = __builtin_amdgcn_permlane32_swap(b1, b3, false, false);
        const u32x2 sB46 = __builtin_amdgcn_permlane32_swap(b4, b6, false, false);
        const u32x2 sB57 = __builtin_amdgcn_permlane32_swap(b5, b7, false, false);
        const h8 A1m0 = __builtin_bit_cast(h8, (u32x4){sA02.x, sA13.x, sA02.y, sA13.y});
        const h8 A2m0 = __builtin_bit_cast(h8, (u32x4){sA46.x, sA57.x, sA46.y, sA57.y});
        const h8 A1m1 = __builtin_bit_cast(h8, (u32x4){sB02.x, sB13.x, sB02.y, sB13.y});
        const h8 A2m1 = __builtin_bit_cast(h8, (u32x4){sB46.x, sB57.x, sB46.y, sB57.y});

        pv0 = MFMA_32(A1m0, Bv1, pv0);
        pv0 = MFMA_32(A2m0, Bv2, pv0);
        pv1 = MFMA_32(A1m1, Bv1, pv1);
        pv1 = MFMA_32(A2m1, Bv2, pv1);
    }

    // epilogue: Z[mrow] sits in cols 16-31 (lane 16+32hi has col 16).
    const int kk = (NH_ - 1 - n) * 16 + l16;
    const int zlane = 16 + 32 * hi;
    _Float16* Hb = Ht + (size_t)b * 512 * 128;
    #pragma unroll
    for (int r = 0; r < 16; ++r) {
        const int mrow = (r & 3) + 8 * (r >> 2) + 4 * hi;
        const float zr0 = __shfl(pv0[r], zlane);
        const float zr1 = __shfl(pv1[r], zlane);
        const float rz0 = __builtin_amdgcn_rcpf(zr0);
        const float rz1 = __builtin_amdgcn_rcpf(zr1);
        if (lm < 16) {
            Hb[(size_t)(m0 + mrow) * 128 + kk]      = (_Float16)(pv0[r] * rz0);
            Hb[(size_t)(m0 + 32 + mrow) * 128 + kk] = (_Float16)(pv1[r] * rz1);
        }
    }
}

// ---------------------------------------------------------------------------
// Kernel B: out[b] = Wo[b] (128x128) @ heads[b] (128x512), fp16 MFMA,
// pure-register. grid (8 col-tiles, 32 b), 512 thr; wave = 16-row m-tile.
// ---------------------------------------------------------------------------
__global__ __launch_bounds__(512) void out_proj_mfma(
    const float* __restrict__ Wo,        // [B][128][128]
    const _Float16* __restrict__ Ht,     // [B][512][128]
    float* __restrict__ out)             // [B][128][512]
{
    const int ct = blockIdx.x;     // col0 = ct*64
    const int b  = blockIdx.y;
    const int t  = threadIdx.x;
    const int wv = t >> 6;
    const int ln = t & 63;
    const int l16 = ln & 15;
    const int g4  = ln >> 4;

    const float* Wb = Wo + (size_t)b * D_ * D_;
    const _Float16* Hb = Ht + (size_t)b * 512 * 128;

    f32x4 acc[4];
    #pragma unroll
    for (int nt = 0; nt < 4; ++nt) acc[nt] = (f32x4){0.f,0.f,0.f,0.f};

    #pragma unroll
    for (int ks = 0; ks < 4; ++ks) {
        const int k0 = ks * 32 + g4 * 8;
        const float* ap = Wb + (size_t)(wv * 16 + l16) * D_ + k0;
        const f32x4 w0 = *(const f32x4*)ap, w1 = *(const f32x4*)(ap + 4);
        h8 Ah;
        #pragma unroll
        for (int j = 0; j < 4; ++j) {
            Ah[j] = (_Float16)w0[j]; Ah[j + 4] = (_Float16)w1[j];
        }
        #pragma unroll
        for (int nt = 0; nt < 4; ++nt) {
            const h8 Bh = *(const h8*)&Hb[(size_t)(ct * 64 + nt * 16 + l16) * 128 + k0];
            acc[nt] = MFMA_K32(Ah, Bh, acc[nt]);
        }
    }

    float* ob = out + (size_t)b * D_ * L_;
    #pragma unroll
    for (int nt = 0; nt < 4; ++nt) {
        #pragma unroll
        for (int r = 0; r < 4; ++r) {
            ob[(size_t)(wv * 16 + g4 * 4 + r) * L_ + ct * 64 + nt * 16 + l16] = acc[nt][r];
        }
    }
}

extern "C" void kernel_launch(void* const* d_in, const int* in_sizes, int n_in,
                              void* d_out, int out_size, void* d_ws, size_t ws_size,
                              hipStream_t stream)
{
    const float* x  = (const float*)d_in[0];
    const float* Wq = (const float*)d_in[1];
    const float* Wk = (const float*)d_in[2];
    const float* Wv = (const float*)d_in[3];
    const float* Wo = (const float*)d_in[4];
    float* out = (float*)d_out;

    _Float16* Ht = (_Float16*)d_ws;                       // 4 MB

    attn_mfma<<<dim3(NH_ * B_), dim3(512), 0, stream>>>(x, Wq, Wk, Wv, Ht);
    out_proj_mfma<<<dim3(8, B_), dim3(512), 0, stream>>>(Wo, Ht, out);
}